// Round 1
// baseline (749.478 us; speedup 1.0000x reference)
//
#include <hip/hip_runtime.h>
#include <math.h>

#define N_NODES 50000
#define N_EDGES 800000
#define F_IN    116
#define HID     32
#define HEADS   4
#define NGRAPH  100
#define IN1     (F_IN + HID)    // 148
#define IN2     (HID * HEADS)   // 128

// ---------- CSR build ----------
__global__ void k_count(const int* __restrict__ ei, const float* __restrict__ attr,
                        int* __restrict__ cnt, float* __restrict__ ssum, int E) {
    int e = blockIdx.x * blockDim.x + threadIdx.x;
    if (e >= E) return;
    int d = ei[E + e];
    atomicAdd(&cnt[d], 1);
    atomicAdd(&ssum[d], attr[e]);
}

__global__ void k_scan(const int* __restrict__ cnt, int* __restrict__ offs, int n) {
    __shared__ int lds[256];
    int t = threadIdx.x;
    int chunk = (n + 255) / 256;
    int base = t * chunk;
    int lim = min(base + chunk, n);
    int local = 0;
    for (int i = base; i < lim; ++i) local += cnt[i];
    lds[t] = local;
    __syncthreads();
    for (int off = 1; off < 256; off <<= 1) {
        int v = (t >= off) ? lds[t - off] : 0;
        __syncthreads();
        lds[t] += v;
        __syncthreads();
    }
    int run = lds[t] - local;   // exclusive prefix
    for (int i = base; i < lim; ++i) { offs[i] = run; run += cnt[i]; }
}

__global__ void k_fill(const int* __restrict__ ei, int* __restrict__ offs,
                       int* __restrict__ csr, int E) {
    int e = blockIdx.x * blockDim.x + threadIdx.x;
    if (e >= E) return;
    int d = ei[E + e];
    int pos = atomicAdd(&offs[d], 1);   // offs becomes "end" after this kernel
    csr[pos] = ei[e];
}

// ---------- GEMM: C[M][BN] = A[M][KTOT] @ W[KTOT][BN] + bias ----------
// FUSED: A is virtual h = [x | We*ssum + be*cnt]
template<int BN, int TN, int KTOT, bool FUSED>
__global__ __launch_bounds__(256)
void k_gemm(const float* __restrict__ A,
            const float* __restrict__ x, const float* __restrict__ ssum,
            const int* __restrict__ cnt, const float* __restrict__ We,
            const float* __restrict__ be,
            const float* __restrict__ W, const float* __restrict__ bias,
            float* __restrict__ C, int M) {
    const int BM = 64, BK = 16, TM = 4;
    __shared__ float As[BM][BK + 1];
    __shared__ float Ws[BK][BN];
    int tid = threadIdx.x;
    int tx = tid & 15, ty = tid >> 4;
    int rowBase = blockIdx.x * BM;
    float acc[TM][TN];
#pragma unroll
    for (int i = 0; i < TM; ++i)
#pragma unroll
        for (int j = 0; j < TN; ++j) acc[i][j] = 0.f;

    for (int k0 = 0; k0 < KTOT; k0 += BK) {
        // A tile: 4 elems/thread
        {
            int r = tid >> 2;
            int kc = (tid & 3) * 4;
            int row = rowBase + r;
#pragma unroll
            for (int u = 0; u < 4; ++u) {
                int k = k0 + kc + u;
                float v = 0.f;
                if (row < M && k < KTOT) {
                    if constexpr (FUSED) {
                        if (k < F_IN) v = x[row * F_IN + k];
                        else {
                            int j2 = k - F_IN;
                            v = We[j2] * ssum[row] + be[j2] * (float)cnt[row];
                        }
                    } else {
                        v = A[row * KTOT + k];
                    }
                }
                As[r][kc + u] = v;
            }
        }
        // W tile
        for (int f = tid; f < BK * BN; f += 256) {
            int kr = f / BN, cc = f % BN;
            int k = k0 + kr;
            Ws[kr][cc] = (k < KTOT) ? W[k * BN + cc] : 0.f;
        }
        __syncthreads();
#pragma unroll
        for (int kk = 0; kk < BK; ++kk) {
            float a[TM], b[TN];
#pragma unroll
            for (int i = 0; i < TM; ++i) a[i] = As[ty * TM + i][kk];
#pragma unroll
            for (int j = 0; j < TN; ++j) b[j] = Ws[kk][tx * TN + j];
#pragma unroll
            for (int i = 0; i < TM; ++i)
#pragma unroll
                for (int j = 0; j < TN; ++j) acc[i][j] += a[i] * b[j];
        }
        __syncthreads();
    }
#pragma unroll
    for (int i = 0; i < TM; ++i) {
        int row = rowBase + ty * TM + i;
        if (row >= M) continue;
#pragma unroll
        for (int j = 0; j < TN; ++j) {
            int col = tx * TN + j;
            C[row * BN + col] = acc[i][j] + bias[col];
        }
    }
}

// ---------- conv1: heads=4, ch=32. One wave per node, online softmax ----------
__global__ __launch_bounds__(256)
void k_conv1(const float* __restrict__ xl, const float* __restrict__ xr,
             const int* __restrict__ csr, const int* __restrict__ offs_end,
             const int* __restrict__ cnt, const float* __restrict__ att,
             const float* __restrict__ bias, float* __restrict__ out, int n_nodes) {
    int wave = threadIdx.x >> 6;
    int lane = threadIdx.x & 63;
    int n = blockIdx.x * 4 + wave;
    if (n >= n_nodes) return;
    int c_n = cnt[n];
    int start = offs_end[n] - c_n;
    int total = c_n + 1;                 // + self loop
    float xr_a = xr[n * 128 + lane];
    float xr_b = xr[n * 128 + 64 + lane];
    float att_a = att[lane], att_b = att[64 + lane];
    float m_a = -INFINITY, m_b = -INFINITY;
    float s_a = 0.f, s_b = 0.f, acc_a = 0.f, acc_b = 0.f;
    for (int j = 0; j < total; ++j) {
        int src = (j == 0) ? n : csr[start + j - 1];
        float xj_a = xl[src * 128 + lane];
        float xj_b = xl[src * 128 + 64 + lane];
        float t = xj_a + xr_a;
        float p = att_a * (t > 0.f ? t : 0.2f * t);
        float q = xj_b + xr_b;
        float pb = att_b * (q > 0.f ? q : 0.2f * q);
#pragma unroll
        for (int mk = 16; mk >= 1; mk >>= 1) {
            p  += __shfl_xor(p, mk);
            pb += __shfl_xor(pb, mk);
        }
        // p  = e for head (lane<32 ? 0 : 1); pb = e for head (+2)
        float nm = fmaxf(m_a, p);
        float sc = expf(m_a - nm);
        float pe = expf(p - nm);
        s_a = s_a * sc + pe;
        acc_a = acc_a * sc + pe * xj_a;
        m_a = nm;
        nm = fmaxf(m_b, pb);
        sc = expf(m_b - nm);
        pe = expf(pb - nm);
        s_b = s_b * sc + pe;
        acc_b = acc_b * sc + pe * xj_b;
        m_b = nm;
    }
    float oa = acc_a / (s_a + 1e-16f) + bias[lane];
    float ob = acc_b / (s_b + 1e-16f) + bias[64 + lane];
    out[n * 128 + lane]      = oa > 0.f ? oa : expf(oa) - 1.f;   // ELU
    out[n * 128 + 64 + lane] = ob > 0.f ? ob : expf(ob) - 1.f;
}

// ---------- conv2: heads=1, ch=32. Two nodes per wave ----------
__global__ __launch_bounds__(256)
void k_conv2(const float* __restrict__ xl, const float* __restrict__ xr,
             const int* __restrict__ csr, const int* __restrict__ offs_end,
             const int* __restrict__ cnt, const float* __restrict__ att,
             const float* __restrict__ bias, float* __restrict__ out, int n_nodes) {
    int wave = threadIdx.x >> 6;
    int lane = threadIdx.x & 63;
    int half = lane >> 5;
    int c = lane & 31;
    int n = blockIdx.x * 8 + wave * 2 + half;
    bool nvalid = n < n_nodes;
    int nn = nvalid ? n : 0;
    int c_n = nvalid ? cnt[nn] : -1;     // total=0 for invalid
    int start = offs_end[nn] - max(c_n, 0);
    int total = c_n + 1;
    int t_other = __shfl_xor(total, 32);
    int tmax = max(total, t_other);
    float xr_v = xr[nn * 32 + c];
    float att_v = att[c];
    float m = -INFINITY, s = 0.f, acc = 0.f;
    for (int j = 0; j < tmax; ++j) {
        bool valid = j < total;
        int src = nn;
        if (valid && j > 0) src = csr[start + j - 1];
        float xj = xl[src * 32 + c];
        float t = xj + xr_v;
        float p = att_v * (t > 0.f ? t : 0.2f * t);
#pragma unroll
        for (int mk = 16; mk >= 1; mk >>= 1) p += __shfl_xor(p, mk);
        float e = valid ? p : -INFINITY;
        float nm = fmaxf(m, e);
        float sc = expf(m - nm);
        float pe = expf(e - nm);
        s = s * sc + pe;
        acc = acc * sc + pe * xj;
        m = nm;
    }
    if (nvalid) {
        float o = acc / (s + 1e-16f) + bias[c];
        out[nn * 32 + c] = o > 0.f ? o : expf(o) - 1.f;          // ELU
    }
}

// ---------- mean pool (batch sorted) ----------
__global__ __launch_bounds__(256)
void k_pool(const float* __restrict__ h2, const int* __restrict__ batch,
            float* __restrict__ pooled, float* __restrict__ gcnt, int n_nodes) {
    __shared__ float lp[NGRAPH * HID];
    __shared__ float lc[NGRAPH];
    for (int i = threadIdx.x; i < NGRAPH * HID; i += 256) lp[i] = 0.f;
    for (int i = threadIdx.x; i < NGRAPH; i += 256) lc[i] = 0.f;
    __syncthreads();
    int totalElems = n_nodes * HID;
    int per = (totalElems + gridDim.x - 1) / gridDim.x;
    int s0 = blockIdx.x * per;
    int s1 = min(s0 + per, totalElems);
    for (int i = s0 + threadIdx.x; i < s1; i += 256) {
        int n = i >> 5, c = i & 31;
        int g = batch[n];
        atomicAdd(&lp[g * HID + c], h2[i]);
        if (c == 0) atomicAdd(&lc[g], 1.f);
    }
    __syncthreads();
    for (int i = threadIdx.x; i < NGRAPH * HID; i += 256)
        if (lp[i] != 0.f) atomicAdd(&pooled[i], lp[i]);
    for (int i = threadIdx.x; i < NGRAPH; i += 256)
        if (lc[i] != 0.f) atomicAdd(&gcnt[i], lc[i]);
}

// ---------- final FC + log_softmax ----------
__global__ void k_final(const float* __restrict__ pooled, const float* __restrict__ gcnt,
                        const float* __restrict__ Wfc, const float* __restrict__ bfc,
                        float* __restrict__ out) {
    int g = blockIdx.x * blockDim.x + threadIdx.x;
    if (g >= NGRAPH) return;
    float inv = 1.f / fmaxf(gcnt[g], 1.f);
    float z0 = bfc[0], z1 = bfc[1];
    for (int c = 0; c < HID; ++c) {
        float mv = pooled[g * HID + c] * inv;
        z0 += mv * Wfc[c * 2 + 0];
        z1 += mv * Wfc[c * 2 + 1];
    }
    float mx = fmaxf(z0, z1);
    float lse = mx + logf(expf(z0 - mx) + expf(z1 - mx));
    out[g * 2 + 0] = z0 - lse;
    out[g * 2 + 1] = z1 - lse;
}

extern "C" void kernel_launch(void* const* d_in, const int* in_sizes, int n_in,
                              void* d_out, int out_size, void* d_ws, size_t ws_size,
                              hipStream_t stream) {
    const float* x     = (const float*)d_in[0];
    const float* eattr = (const float*)d_in[1];
    const int*   eidx  = (const int*)d_in[2];
    const int*   batch = (const int*)d_in[3];
    const float* We    = (const float*)d_in[4];
    const float* be    = (const float*)d_in[5];
    const float* W1l   = (const float*)d_in[6];
    const float* b1l   = (const float*)d_in[7];
    const float* W1r   = (const float*)d_in[8];
    const float* b1r   = (const float*)d_in[9];
    const float* att1  = (const float*)d_in[10];
    const float* bias1 = (const float*)d_in[11];
    const float* W2l   = (const float*)d_in[12];
    const float* b2l   = (const float*)d_in[13];
    const float* W2r   = (const float*)d_in[14];
    const float* b2r   = (const float*)d_in[15];
    const float* att2  = (const float*)d_in[16];
    const float* bias2 = (const float*)d_in[17];
    const float* Wfc   = (const float*)d_in[18];
    const float* bfc   = (const float*)d_in[19];
    float* out = (float*)d_out;

    char* ws = (char*)d_ws;
    size_t off = 0;
    auto alloc = [&](size_t bytes) {
        void* p = ws + off;
        off += (bytes + 255) & ~size_t(255);
        return p;
    };
    int*   cnt    = (int*)  alloc(N_NODES * 4);
    int*   offs   = (int*)  alloc(N_NODES * 4);
    float* ssum   = (float*)alloc(N_NODES * 4);
    int*   csr    = (int*)  alloc(N_EDGES * 4);
    float* xl1    = (float*)alloc((size_t)N_NODES * 128 * 4);
    float* xr1    = (float*)alloc((size_t)N_NODES * 128 * 4);
    float* h1     = (float*)alloc((size_t)N_NODES * 128 * 4);
    float* pooled = (float*)alloc(NGRAPH * HID * 4);
    float* gcnt   = (float*)alloc(NGRAPH * 4);
    // xl1/xr1 are dead after conv1 -> reuse their region for conv2 tensors
    float* xl2 = xl1;
    float* xr2 = xl2 + (size_t)N_NODES * 32;
    float* h2  = xr2 + (size_t)N_NODES * 32;
    // total static ws use: ~80.6 MB

    hipMemsetAsync(cnt, 0, N_NODES * 4, stream);
    hipMemsetAsync(ssum, 0, N_NODES * 4, stream);
    hipMemsetAsync(pooled, 0, (NGRAPH * HID + NGRAPH) * 4 + 0, stream);
    hipMemsetAsync(gcnt, 0, NGRAPH * 4, stream);

    int ebl = (N_EDGES + 255) / 256;
    k_count<<<ebl, 256, 0, stream>>>(eidx, eattr, cnt, ssum, N_EDGES);
    k_scan<<<1, 256, 0, stream>>>(cnt, offs, N_NODES);
    k_fill<<<ebl, 256, 0, stream>>>(eidx, offs, csr, N_EDGES);

    int gbl = (N_NODES + 63) / 64;
    k_gemm<128, 8, IN1, true><<<gbl, 256, 0, stream>>>(
        nullptr, x, ssum, cnt, We, be, W1l, b1l, xl1, N_NODES);
    k_gemm<128, 8, IN1, true><<<gbl, 256, 0, stream>>>(
        nullptr, x, ssum, cnt, We, be, W1r, b1r, xr1, N_NODES);

    k_conv1<<<(N_NODES + 3) / 4, 256, 0, stream>>>(
        xl1, xr1, csr, offs, cnt, att1, bias1, h1, N_NODES);

    k_gemm<32, 2, IN2, false><<<gbl, 256, 0, stream>>>(
        h1, nullptr, nullptr, nullptr, nullptr, nullptr, W2l, b2l, xl2, N_NODES);
    k_gemm<32, 2, IN2, false><<<gbl, 256, 0, stream>>>(
        h1, nullptr, nullptr, nullptr, nullptr, nullptr, W2r, b2r, xr2, N_NODES);

    k_conv2<<<(N_NODES + 7) / 8, 256, 0, stream>>>(
        xl2, xr2, csr, offs, cnt, att2, bias2, h2, N_NODES);

    k_pool<<<256, 256, 0, stream>>>(h2, batch, pooled, gcnt, N_NODES);
    k_final<<<1, 128, 0, stream>>>(pooled, gcnt, Wfc, bfc, out);
}

// Round 4
// 673.304 us; speedup vs baseline: 1.1131x; 1.1131x over previous
//
#include <hip/hip_runtime.h>
#include <hip/hip_bf16.h>
#include <math.h>

#define N_NODES 50000
#define N_EDGES 800000
#define F_IN    116
#define HID     32
#define HEADS   4
#define NGRAPH  100
#define IN1     (F_IN + HID)    // 148
#define IN2     (HID * HEADS)   // 128

// exp(x - 30) == exp2(x*log2e - 30*log2e)
#define EXP_SHIFT_MUL  1.44269504f
#define EXP_SHIFT_SUB  43.2808512f

// ---------- CSR build ----------
__global__ void k_count(const int* __restrict__ ei, const float* __restrict__ attr,
                        int* __restrict__ cnt, float* __restrict__ ssum, int E) {
    int e = blockIdx.x * blockDim.x + threadIdx.x;
    if (e >= E) return;
    int d = ei[E + e];
    atomicAdd(&cnt[d], 1);
    atomicAdd(&ssum[d], attr[e]);
}

__global__ __launch_bounds__(1024)
void k_scan(const int* __restrict__ cnt, int* __restrict__ offs, int n) {
    __shared__ int lds[1024];
    int t = threadIdx.x;
    int chunk = (n + 1023) / 1024;
    int base = t * chunk;
    int lim = min(base + chunk, n);
    int local = 0;
    for (int i = base; i < lim; ++i) local += cnt[i];
    lds[t] = local;
    __syncthreads();
    for (int off = 1; off < 1024; off <<= 1) {
        int v = (t >= off) ? lds[t - off] : 0;
        __syncthreads();
        lds[t] += v;
        __syncthreads();
    }
    int run = lds[t] - local;   // exclusive prefix
    for (int i = base; i < lim; ++i) { offs[i] = run; run += cnt[i]; }
}

__global__ void k_fill(const int* __restrict__ ei, int* __restrict__ offs,
                       int* __restrict__ csr, int E) {
    int e = blockIdx.x * blockDim.x + threadIdx.x;
    if (e >= E) return;
    int d = ei[E + e];
    int pos = atomicAdd(&offs[d], 1);   // offs becomes "end" after this kernel
    csr[pos] = ei[e];
}

// ---------- GEMM: C[M][BN] = A[M][KTOT] @ W[KTOT][BN] + bias ----------
// FUSED: A is virtual h = [x | We*ssum + be*cnt].  BF16OUT: store packed bf16.
template<int BN, int TN, int KTOT, bool FUSED, bool BF16OUT>
__global__ __launch_bounds__(256)
void k_gemm(const float* __restrict__ A,
            const float* __restrict__ x, const float* __restrict__ ssum,
            const int* __restrict__ cnt, const float* __restrict__ We,
            const float* __restrict__ be,
            const float* __restrict__ W, const float* __restrict__ bias,
            float* __restrict__ C, unsigned short* __restrict__ Cb, int M) {
    const int BM = 64, BK = 16, TM = 4;
    __shared__ float As[BM][BK + 1];
    __shared__ float Ws[BK][BN];
    int tid = threadIdx.x;
    int tx = tid & 15, ty = tid >> 4;
    int rowBase = blockIdx.x * BM;
    float acc[TM][TN];
#pragma unroll
    for (int i = 0; i < TM; ++i)
#pragma unroll
        for (int j = 0; j < TN; ++j) acc[i][j] = 0.f;

    for (int k0 = 0; k0 < KTOT; k0 += BK) {
        {
            int r = tid >> 2;
            int kc = (tid & 3) * 4;
            int row = rowBase + r;
#pragma unroll
            for (int u = 0; u < 4; ++u) {
                int k = k0 + kc + u;
                float v = 0.f;
                if (row < M && k < KTOT) {
                    if constexpr (FUSED) {
                        if (k < F_IN) v = x[row * F_IN + k];
                        else {
                            int j2 = k - F_IN;
                            v = We[j2] * ssum[row] + be[j2] * (float)cnt[row];
                        }
                    } else {
                        v = A[row * KTOT + k];
                    }
                }
                As[r][kc + u] = v;
            }
        }
        for (int f = tid; f < BK * BN; f += 256) {
            int kr = f / BN, cc = f % BN;
            int k = k0 + kr;
            Ws[kr][cc] = (k < KTOT) ? W[k * BN + cc] : 0.f;
        }
        __syncthreads();
#pragma unroll
        for (int kk = 0; kk < BK; ++kk) {
            float a[TM], b[TN];
#pragma unroll
            for (int i = 0; i < TM; ++i) a[i] = As[ty * TM + i][kk];
#pragma unroll
            for (int j = 0; j < TN; ++j) b[j] = Ws[kk][tx * TN + j];
#pragma unroll
            for (int i = 0; i < TM; ++i)
#pragma unroll
                for (int j = 0; j < TN; ++j) acc[i][j] += a[i] * b[j];
        }
        __syncthreads();
    }
#pragma unroll
    for (int i = 0; i < TM; ++i) {
        int row = rowBase + ty * TM + i;
        if (row >= M) continue;
#pragma unroll
        for (int j = 0; j < TN; ++j) {
            int col = tx * TN + j;
            float v = acc[i][j] + bias[col];
            if constexpr (BF16OUT) {
                Cb[row * BN + col] = (unsigned short)__bfloat16_as_ushort(__float2bfloat16(v));
            } else {
                C[row * BN + col] = v;
            }
        }
    }
}

// ---------- conv1: heads=4 ch=32, bf16-packed inputs, no-max softmax ----------
// xl/xr: packed bf16 pairs, word l of node n = channels (2l, 2l+1), [N, 64] uints
__global__ __launch_bounds__(256)
void k_conv1(const unsigned* __restrict__ xl, const unsigned* __restrict__ xr,
             const int* __restrict__ csr, const int* __restrict__ offs_end,
             const int* __restrict__ cnt, const float* __restrict__ att,
             const float* __restrict__ bias, float* __restrict__ out, int n_nodes) {
    int wave = threadIdx.x >> 6;
    int lane = threadIdx.x & 63;
    int n = blockIdx.x * 4 + wave;
    if (n >= n_nodes) return;
    int c_n = cnt[n];
    int start = offs_end[n] - c_n;
    int total = c_n + 1;                 // + self loop

    unsigned ur = xr[n * 64 + lane];
    float xr0 = __uint_as_float(ur << 16);
    float xr1 = __uint_as_float(ur & 0xffff0000u);
    float2 av = *(const float2*)(att + 2 * lane);
    float att0 = av.x, att1 = av.y;

    float s = 0.f, acc0 = 0.f, acc1 = 0.f;
    for (int j = 0; j < total; ++j) {
        int src = (j == 0) ? n : csr[start + j - 1];
        unsigned u = xl[src * 64 + lane];
        float x0 = __uint_as_float(u << 16);
        float x1 = __uint_as_float(u & 0xffff0000u);
        float v0 = x0 + xr0;
        float v1 = x1 + xr1;
        float l0 = fmaxf(v0, 0.f) + 0.2f * fminf(v0, 0.f);
        float l1 = fmaxf(v1, 0.f) + 0.2f * fminf(v1, 0.f);
        float p = att0 * l0 + att1 * l1;
        // reduce over the 16-lane head group (channels h*32..h*32+31)
        p += __shfl_xor(p, 1);
        p += __shfl_xor(p, 2);
        p += __shfl_xor(p, 4);
        p += __shfl_xor(p, 8);
        float ez = exp2f(p * EXP_SHIFT_MUL - EXP_SHIFT_SUB);   // exp(p-30)
        s += ez;
        acc0 += ez * x0;
        acc1 += ez * x1;
    }
    float inv = 1.f / s;
    float2 bv = *(const float2*)(bias + 2 * lane);
    float o0 = acc0 * inv + bv.x;
    float o1 = acc1 * inv + bv.y;
    o0 = o0 > 0.f ? o0 : __expf(o0) - 1.f;                     // ELU
    o1 = o1 > 0.f ? o1 : __expf(o1) - 1.f;
    *(float2*)(out + n * 128 + 2 * lane) = make_float2(o0, o1);
}

// ---------- conv2: heads=1 ch=32, fp32, no-max softmax, 2 nodes/wave ----------
__global__ __launch_bounds__(256)
void k_conv2(const float* __restrict__ xl, const float* __restrict__ xr,
             const int* __restrict__ csr, const int* __restrict__ offs_end,
             const int* __restrict__ cnt, const float* __restrict__ att,
             const float* __restrict__ bias, float* __restrict__ out, int n_nodes) {
    int wave = threadIdx.x >> 6;
    int lane = threadIdx.x & 63;
    int half = lane >> 5;
    int c = lane & 31;
    int n = blockIdx.x * 8 + wave * 2 + half;
    bool nvalid = n < n_nodes;
    int nn = nvalid ? n : 0;
    int c_n = nvalid ? cnt[nn] : -1;     // total=0 for invalid
    int start = offs_end[nn] - max(c_n, 0);
    int total = c_n + 1;
    int t_other = __shfl_xor(total, 32);
    int tmax = max(total, t_other);
    float xr_v = xr[nn * 32 + c];
    float att_v = att[c];
    float s = 0.f, acc = 0.f;
    for (int j = 0; j < tmax; ++j) {
        bool valid = j < total;
        int src = nn;
        if (valid && j > 0) src = csr[start + j - 1];
        float xj = xl[src * 32 + c];
        float t = xj + xr_v;
        float lk = fmaxf(t, 0.f) + 0.2f * fminf(t, 0.f);
        float p = att_v * lk;
#pragma unroll
        for (int mk = 16; mk >= 1; mk >>= 1) p += __shfl_xor(p, mk);
        float ez = exp2f(p * EXP_SHIFT_MUL - EXP_SHIFT_SUB);   // exp(p-30)
        ez = valid ? ez : 0.f;
        s += ez;
        acc += ez * xj;
    }
    if (nvalid) {
        float o = acc / s + bias[c];
        out[nn * 32 + c] = o > 0.f ? o : __expf(o) - 1.f;      // ELU
    }
}

// ---------- mean pool (batch sorted) ----------
__global__ __launch_bounds__(256)
void k_pool(const float* __restrict__ h2, const int* __restrict__ batch,
            float* __restrict__ pooled, float* __restrict__ gcnt, int n_nodes) {
    __shared__ float lp[NGRAPH * HID];
    __shared__ float lc[NGRAPH];
    for (int i = threadIdx.x; i < NGRAPH * HID; i += 256) lp[i] = 0.f;
    for (int i = threadIdx.x; i < NGRAPH; i += 256) lc[i] = 0.f;
    __syncthreads();
    int totalElems = n_nodes * HID;
    int per = (totalElems + gridDim.x - 1) / gridDim.x;
    int s0 = blockIdx.x * per;
    int s1 = min(s0 + per, totalElems);
    for (int i = s0 + threadIdx.x; i < s1; i += 256) {
        int n = i >> 5, cc = i & 31;
        int g = batch[n];
        atomicAdd(&lp[g * HID + cc], h2[i]);
        if (cc == 0) atomicAdd(&lc[g], 1.f);
    }
    __syncthreads();
    for (int i = threadIdx.x; i < NGRAPH * HID; i += 256)
        if (lp[i] != 0.f) atomicAdd(&pooled[i], lp[i]);
    for (int i = threadIdx.x; i < NGRAPH; i += 256)
        if (lc[i] != 0.f) atomicAdd(&gcnt[i], lc[i]);
}

// ---------- final FC + log_softmax ----------
__global__ void k_final(const float* __restrict__ pooled, const float* __restrict__ gcnt,
                        const float* __restrict__ Wfc, const float* __restrict__ bfc,
                        float* __restrict__ out) {
    int g = blockIdx.x * blockDim.x + threadIdx.x;
    if (g >= NGRAPH) return;
    float inv = 1.f / fmaxf(gcnt[g], 1.f);
    float z0 = bfc[0], z1 = bfc[1];
    for (int c = 0; c < HID; ++c) {
        float mv = pooled[g * HID + c] * inv;
        z0 += mv * Wfc[c * 2 + 0];
        z1 += mv * Wfc[c * 2 + 1];
    }
    float mx = fmaxf(z0, z1);
    float lse = mx + logf(expf(z0 - mx) + expf(z1 - mx));
    out[g * 2 + 0] = z0 - lse;
    out[g * 2 + 1] = z1 - lse;
}

extern "C" void kernel_launch(void* const* d_in, const int* in_sizes, int n_in,
                              void* d_out, int out_size, void* d_ws, size_t ws_size,
                              hipStream_t stream) {
    const float* x     = (const float*)d_in[0];
    const float* eattr = (const float*)d_in[1];
    const int*   eidx  = (const int*)d_in[2];
    const int*   batch = (const int*)d_in[3];
    const float* We    = (const float*)d_in[4];
    const float* be    = (const float*)d_in[5];
    const float* W1l   = (const float*)d_in[6];
    const float* b1l   = (const float*)d_in[7];
    const float* W1r   = (const float*)d_in[8];
    const float* b1r   = (const float*)d_in[9];
    const float* att1  = (const float*)d_in[10];
    const float* bias1 = (const float*)d_in[11];
    const float* W2l   = (const float*)d_in[12];
    const float* b2l   = (const float*)d_in[13];
    const float* W2r   = (const float*)d_in[14];
    const float* b2r   = (const float*)d_in[15];
    const float* att2  = (const float*)d_in[16];
    const float* bias2 = (const float*)d_in[17];
    const float* Wfc   = (const float*)d_in[18];
    const float* bfc   = (const float*)d_in[19];
    float* out = (float*)d_out;

    char* ws = (char*)d_ws;
    size_t off = 0;
    auto alloc = [&](size_t bytes) {
        void* p = ws + off;
        off += (bytes + 255) & ~size_t(255);
        return p;
    };
    int*      cnt    = (int*)     alloc(N_NODES * 4);
    int*      offs   = (int*)     alloc(N_NODES * 4);
    float*    ssum   = (float*)   alloc(N_NODES * 4);
    int*      csr    = (int*)     alloc(N_EDGES * 4);
    unsigned* xl1    = (unsigned*)alloc((size_t)N_NODES * 64 * 4);   // bf16-packed [N,128]
    unsigned* xr1    = (unsigned*)alloc((size_t)N_NODES * 64 * 4);
    float*    h1     = (float*)   alloc((size_t)N_NODES * 128 * 4);
    float*    pooled = (float*)   alloc(NGRAPH * HID * 4);
    float*    gcnt   = (float*)   alloc(NGRAPH * 4);
    // xl1/xr1 dead after conv1 -> reuse region for conv2 fp32 tensors
    float* xl2 = (float*)xl1;
    float* xr2 = xl2 + (size_t)N_NODES * 32;
    float* h2  = xr2 + (size_t)N_NODES * 32;   // 3*6.4MB fits in xl1+xr1 (25.6MB)

    hipMemsetAsync(cnt, 0, N_NODES * 4, stream);
    hipMemsetAsync(ssum, 0, N_NODES * 4, stream);
    hipMemsetAsync(pooled, 0, NGRAPH * HID * 4, stream);
    hipMemsetAsync(gcnt, 0, NGRAPH * 4, stream);

    int ebl = (N_EDGES + 255) / 256;
    k_count<<<ebl, 256, 0, stream>>>(eidx, eattr, cnt, ssum, N_EDGES);
    k_scan<<<1, 1024, 0, stream>>>(cnt, offs, N_NODES);
    k_fill<<<ebl, 256, 0, stream>>>(eidx, offs, csr, N_EDGES);

    int gbl = (N_NODES + 63) / 64;
    k_gemm<128, 8, IN1, true, true><<<gbl, 256, 0, stream>>>(
        nullptr, x, ssum, cnt, We, be, W1l, b1l, nullptr, (unsigned short*)xl1, N_NODES);
    k_gemm<128, 8, IN1, true, true><<<gbl, 256, 0, stream>>>(
        nullptr, x, ssum, cnt, We, be, W1r, b1r, nullptr, (unsigned short*)xr1, N_NODES);

    k_conv1<<<(N_NODES + 3) / 4, 256, 0, stream>>>(
        xl1, xr1, csr, offs, cnt, att1, bias1, h1, N_NODES);

    k_gemm<32, 2, IN2, false, false><<<gbl, 256, 0, stream>>>(
        h1, nullptr, nullptr, nullptr, nullptr, nullptr, W2l, b2l, xl2, nullptr, N_NODES);
    k_gemm<32, 2, IN2, false, false><<<gbl, 256, 0, stream>>>(
        h1, nullptr, nullptr, nullptr, nullptr, nullptr, W2r, b2r, xr2, nullptr, N_NODES);

    k_conv2<<<(N_NODES + 7) / 8, 256, 0, stream>>>(
        xl2, xr2, csr, offs, cnt, att2, bias2, h2, N_NODES);

    k_pool<<<256, 256, 0, stream>>>(h2, batch, pooled, gcnt, N_NODES);
    k_final<<<1, 128, 0, stream>>>(pooled, gcnt, Wfc, bfc, out);
}

// Round 6
// 474.244 us; speedup vs baseline: 1.5804x; 1.4197x over previous
//
#include <hip/hip_runtime.h>
#include <hip/hip_bf16.h>
#include <math.h>

#define N_NODES 50000
#define N_EDGES 800000
#define F_IN    116
#define HID     32
#define HEADS   4
#define NGRAPH  100
#define IN1     (F_IN + HID)    // 148
#define IN2     (HID * HEADS)   // 128

// exp(x - 30) == exp2(x*log2e - 30*log2e)
#define EXP_SHIFT_MUL  1.44269504f
#define EXP_SHIFT_SUB  43.2808512f

typedef __attribute__((ext_vector_type(8))) short bf16x8;
typedef __attribute__((ext_vector_type(4))) float f32x4;

__device__ inline unsigned pack_bf2(float a, float b) {
    unsigned lo = __bfloat16_as_ushort(__float2bfloat16(a));
    unsigned hi = __bfloat16_as_ushort(__float2bfloat16(b));
    return lo | (hi << 16);
}

// ---------- CSR build ----------
__global__ void k_count(const int* __restrict__ ei, const float* __restrict__ attr,
                        int* __restrict__ cnt, float* __restrict__ ssum, int E) {
    int e = blockIdx.x * blockDim.x + threadIdx.x;
    if (e >= E) return;
    int d = ei[E + e];
    atomicAdd(&cnt[d], 1);
    atomicAdd(&ssum[d], attr[e]);
}

__global__ __launch_bounds__(1024)
void k_scan(const int* __restrict__ cnt, int* __restrict__ offs, int n) {
    __shared__ int lds[1024];
    int t = threadIdx.x;
    int chunk = (n + 1023) / 1024;
    int base = t * chunk;
    int lim = min(base + chunk, n);
    int local = 0;
    for (int i = base; i < lim; ++i) local += cnt[i];
    lds[t] = local;
    __syncthreads();
    for (int off = 1; off < 1024; off <<= 1) {
        int v = (t >= off) ? lds[t - off] : 0;
        __syncthreads();
        lds[t] += v;
        __syncthreads();
    }
    int run = lds[t] - local;   // exclusive prefix
    for (int i = base; i < lim; ++i) { offs[i] = run; run += cnt[i]; }
}

__global__ void k_fill(const int* __restrict__ ei, int* __restrict__ offs,
                       int* __restrict__ csr, int E) {
    int e = blockIdx.x * blockDim.x + threadIdx.x;
    if (e >= E) return;
    int d = ei[E + e];
    int pos = atomicAdd(&offs[d], 1);   // offs becomes "end" after this kernel
    csr[pos] = ei[e];
}

// ---------- MFMA GEMM 1: C[M][128] = hcat(x, edge_msg)[M][148] @ W + bias ----------
// Whole K resident in LDS (pad 148->168). Output bf16-packed u16.
#define KPAD1 168
__global__ __launch_bounds__(256)
void k_mm1(const float* __restrict__ x, const float* __restrict__ ssum,
           const int* __restrict__ cnt, const float* __restrict__ We,
           const float* __restrict__ be, const float* __restrict__ W,
           const float* __restrict__ bias, unsigned short* __restrict__ Cb, int M) {
    __shared__ short As[64][KPAD1];
    __shared__ short Ws[128][KPAD1];
    int tid = threadIdx.x;
    int rowBase = blockIdx.x * 64;
    // stage A (64 rows x 84 bf16-pairs): fp32 -> bf16, fused edge_msg for k>=116
    {
        int r = tid >> 2;
        int p0 = tid & 3;
        int row = rowBase + r;
        bool rv = row < M;
        float ss = rv ? ssum[row] : 0.f;
        float cf = rv ? (float)cnt[row] : 0.f;
        const float* xrp = x + (size_t)row * F_IN;
#pragma unroll
        for (int i = 0; i < 21; ++i) {
            int p = p0 + i * 4;
            int k = 2 * p;
            float v0 = 0.f, v1 = 0.f;
            if (rv && k < IN1) {
                if (k < F_IN) {
                    float2 t = *(const float2*)(xrp + k);
                    v0 = t.x; v1 = t.y;
                } else {
                    int j = k - F_IN;
                    v0 = We[j] * ss + be[j] * cf;
                    v1 = We[j + 1] * ss + be[j + 1] * cf;
                }
            }
            ((int*)&As[r][0])[p] = (int)pack_bf2(v0, v1);
        }
    }
    // stage W^T (128 cols x 84 bf16-pairs)
    {
        int c = tid & 127;
        int ph = tid >> 7;
#pragma unroll
        for (int i = 0; i < 42; ++i) {
            int p = ph + 2 * i;
            int k = 2 * p;
            float v0 = (k < IN1) ? W[k * 128 + c] : 0.f;
            float v1 = (k + 1 < IN1) ? W[(k + 1) * 128 + c] : 0.f;
            ((int*)&Ws[c][0])[p] = (int)pack_bf2(v0, v1);
        }
    }
    __syncthreads();

    int wid = tid >> 6, l = tid & 63;
    int wm = wid >> 1, wn = wid & 1;
    int mBase = wm * 32, nBase = wn * 64;
    int lr = l & 15, lg = l >> 4;
    f32x4 acc[2][4] = {};
#pragma unroll
    for (int ks = 0; ks < 5; ++ks) {
        int k0 = ks * 32 + lg * 8;
        bf16x8 a0 = *(bf16x8*)&As[mBase + lr][k0];
        bf16x8 a1 = *(bf16x8*)&As[mBase + 16 + lr][k0];
        bf16x8 b0 = *(bf16x8*)&Ws[nBase + lr][k0];
        bf16x8 b1 = *(bf16x8*)&Ws[nBase + 16 + lr][k0];
        bf16x8 b2 = *(bf16x8*)&Ws[nBase + 32 + lr][k0];
        bf16x8 b3 = *(bf16x8*)&Ws[nBase + 48 + lr][k0];
        acc[0][0] = __builtin_amdgcn_mfma_f32_16x16x32_bf16(a0, b0, acc[0][0], 0, 0, 0);
        acc[0][1] = __builtin_amdgcn_mfma_f32_16x16x32_bf16(a0, b1, acc[0][1], 0, 0, 0);
        acc[0][2] = __builtin_amdgcn_mfma_f32_16x16x32_bf16(a0, b2, acc[0][2], 0, 0, 0);
        acc[0][3] = __builtin_amdgcn_mfma_f32_16x16x32_bf16(a0, b3, acc[0][3], 0, 0, 0);
        acc[1][0] = __builtin_amdgcn_mfma_f32_16x16x32_bf16(a1, b0, acc[1][0], 0, 0, 0);
        acc[1][1] = __builtin_amdgcn_mfma_f32_16x16x32_bf16(a1, b1, acc[1][1], 0, 0, 0);
        acc[1][2] = __builtin_amdgcn_mfma_f32_16x16x32_bf16(a1, b2, acc[1][2], 0, 0, 0);
        acc[1][3] = __builtin_amdgcn_mfma_f32_16x16x32_bf16(a1, b3, acc[1][3], 0, 0, 0);
    }
#pragma unroll
    for (int mf = 0; mf < 2; ++mf)
#pragma unroll
        for (int nf = 0; nf < 4; ++nf) {
            int col = nBase + nf * 16 + lr;
            float bs = bias[col];
#pragma unroll
            for (int r = 0; r < 4; ++r) {
                int row = rowBase + mBase + mf * 16 + lg * 4 + r;
                if (row < M)
                    Cb[(size_t)row * 128 + col] =
                        __bfloat16_as_ushort(__float2bfloat16(acc[mf][nf][r] + bs));
            }
        }
}

// ---------- MFMA GEMM 2 (fused l|r): [xl2|xr2] = h1[M][128] @ [W2l|W2r] + b ----------
#define KPAD2 136
__global__ __launch_bounds__(256)
void k_mm2(const unsigned* __restrict__ h1, const float* __restrict__ Wl,
           const float* __restrict__ bl, const float* __restrict__ Wr,
           const float* __restrict__ br, float* __restrict__ xl2,
           float* __restrict__ xr2, int M) {
    __shared__ short As[64][KPAD2];
    __shared__ short Ws[64][KPAD2];
    int tid = threadIdx.x;
    int rowBase = blockIdx.x * 64;
    // stage A from bf16-packed h1 (64 rows x 68 uint slots)
    {
        int r = tid >> 2;
        int s0 = tid & 3;
        int row = rowBase + r;
        bool rv = row < M;
#pragma unroll
        for (int i = 0; i < 17; ++i) {
            int slot = s0 + 4 * i;
            unsigned u = (rv && slot < 64) ? h1[(size_t)row * 64 + slot] : 0u;
            ((int*)&As[r][0])[slot] = (int)u;
        }
    }
    // stage [W2l|W2r]^T (64 cols x 68 pairs)
    {
        int c = tid & 63;
        int ph = tid >> 6;
#pragma unroll
        for (int i = 0; i < 17; ++i) {
            int p = ph + 4 * i;
            int k = 2 * p;
            float v0 = 0.f, v1 = 0.f;
            if (k < IN2) {
                if (c < 32) { v0 = Wl[k * 32 + c]; v1 = Wl[(k + 1) * 32 + c]; }
                else        { v0 = Wr[k * 32 + c - 32]; v1 = Wr[(k + 1) * 32 + c - 32]; }
            }
            ((int*)&Ws[c][0])[p] = (int)pack_bf2(v0, v1);
        }
    }
    __syncthreads();

    int wid = tid >> 6, l = tid & 63;
    int wm = wid >> 1, wn = wid & 1;
    int mBase = wm * 32, nBase = wn * 32;
    int lr = l & 15, lg = l >> 4;
    f32x4 acc[2][2] = {};
#pragma unroll
    for (int ks = 0; ks < 4; ++ks) {
        int k0 = ks * 32 + lg * 8;
        bf16x8 a0 = *(bf16x8*)&As[mBase + lr][k0];
        bf16x8 a1 = *(bf16x8*)&As[mBase + 16 + lr][k0];
        bf16x8 b0 = *(bf16x8*)&Ws[nBase + lr][k0];
        bf16x8 b1 = *(bf16x8*)&Ws[nBase + 16 + lr][k0];
        acc[0][0] = __builtin_amdgcn_mfma_f32_16x16x32_bf16(a0, b0, acc[0][0], 0, 0, 0);
        acc[0][1] = __builtin_amdgcn_mfma_f32_16x16x32_bf16(a0, b1, acc[0][1], 0, 0, 0);
        acc[1][0] = __builtin_amdgcn_mfma_f32_16x16x32_bf16(a1, b0, acc[1][0], 0, 0, 0);
        acc[1][1] = __builtin_amdgcn_mfma_f32_16x16x32_bf16(a1, b1, acc[1][1], 0, 0, 0);
    }
#pragma unroll
    for (int mf = 0; mf < 2; ++mf)
#pragma unroll
        for (int nf = 0; nf < 2; ++nf) {
            int cg = nBase + nf * 16 + lr;
#pragma unroll
            for (int r = 0; r < 4; ++r) {
                int row = rowBase + mBase + mf * 16 + lg * 4 + r;
                if (row < M) {
                    float v = acc[mf][nf][r];
                    if (cg < 32) xl2[(size_t)row * 32 + cg] = v + bl[cg];
                    else         xr2[(size_t)row * 32 + cg - 32] = v + br[cg - 32];
                }
            }
        }
}

// ---------- conv1: heads=4 ch=32, bf16 inputs, 2 edges/iter, depth-2 prefetch ----------
// xl/xr: bf16-packed [N,64] uints. out h1: bf16-packed [N,64] uints.
__global__ __launch_bounds__(256)
void k_conv1(const unsigned* __restrict__ xl, const unsigned* __restrict__ xr,
             const int* __restrict__ csr, const int* __restrict__ offs_end,
             const int* __restrict__ cnt, const float* __restrict__ att,
             const float* __restrict__ bias, unsigned* __restrict__ h1, int n_nodes) {
    int wave = threadIdx.x >> 6;
    int lane = threadIdx.x & 63;
    int half = lane >> 5;
    int l32 = lane & 31;
    int n = blockIdx.x * 4 + wave;
    if (n >= n_nodes) return;
    int c_n = cnt[n];
    int start = offs_end[n] - c_n;
    int total = c_n + 1;                     // + self loop

    uint2 urv = *(const uint2*)(xr + (size_t)n * 64 + 2 * l32);
    float xr0 = __uint_as_float(urv.x << 16);
    float xr1 = __uint_as_float(urv.x & 0xffff0000u);
    float xr2v = __uint_as_float(urv.y << 16);
    float xr3 = __uint_as_float(urv.y & 0xffff0000u);
    float4 av = *(const float4*)(att + 4 * l32);

    int tmax = (total + 1) >> 1;
    // item(t) = 2t + half; item 0 = self, item i>=1 -> csr[start+i-1]
    int item0 = half;
    bool v_cur = item0 < total;
    int src_cur = (item0 == 0 || !v_cur) ? n : csr[start];
    uint2 u_cur = *(const uint2*)(xl + (size_t)src_cur * 64 + 2 * l32);
    int item1 = 2 + half;
    bool v_n = item1 < total;
    int src_n = v_n ? csr[start + item1 - 1] : n;

    float s = 0.f, a0 = 0.f, a1 = 0.f, a2 = 0.f, a3 = 0.f;
    for (int t = 0; t < tmax; ++t) {
        uint2 u_next = *(const uint2*)(xl + (size_t)src_n * 64 + 2 * l32);
        int item2 = 2 * (t + 2) + half;
        bool v_n2 = item2 < total;
        int src_n2 = v_n2 ? csr[start + item2 - 1] : n;

        float x0 = __uint_as_float(u_cur.x << 16);
        float x1 = __uint_as_float(u_cur.x & 0xffff0000u);
        float x2 = __uint_as_float(u_cur.y << 16);
        float x3 = __uint_as_float(u_cur.y & 0xffff0000u);
        float t0 = x0 + xr0, t1 = x1 + xr1, t2 = x2 + xr2v, t3 = x3 + xr3;
        float p = av.x * (fmaxf(t0, 0.f) + 0.2f * fminf(t0, 0.f))
                + av.y * (fmaxf(t1, 0.f) + 0.2f * fminf(t1, 0.f))
                + av.z * (fmaxf(t2, 0.f) + 0.2f * fminf(t2, 0.f))
                + av.w * (fmaxf(t3, 0.f) + 0.2f * fminf(t3, 0.f));
        // reduce over 8-lane head group
        p += __shfl_xor(p, 1);
        p += __shfl_xor(p, 2);
        p += __shfl_xor(p, 4);
        float ez = v_cur ? exp2f(p * EXP_SHIFT_MUL - EXP_SHIFT_SUB) : 0.f;
        s += ez;
        a0 += ez * x0; a1 += ez * x1; a2 += ez * x2; a3 += ez * x3;

        u_cur = u_next; v_cur = v_n; v_n = v_n2; src_n = src_n2;
    }
    // merge the two halves (even/odd edge partial sums)
    s  += __shfl_xor(s, 32);
    a0 += __shfl_xor(a0, 32);
    a1 += __shfl_xor(a1, 32);
    a2 += __shfl_xor(a2, 32);
    a3 += __shfl_xor(a3, 32);
    if (half == 0) {
        float inv = 1.f / s;
        float4 bv = *(const float4*)(bias + 4 * l32);
        float o0 = a0 * inv + bv.x;
        float o1 = a1 * inv + bv.y;
        float o2 = a2 * inv + bv.z;
        float o3 = a3 * inv + bv.w;
        o0 = o0 > 0.f ? o0 : __expf(o0) - 1.f;   // ELU
        o1 = o1 > 0.f ? o1 : __expf(o1) - 1.f;
        o2 = o2 > 0.f ? o2 : __expf(o2) - 1.f;
        o3 = o3 > 0.f ? o3 : __expf(o3) - 1.f;
        uint2 w;
        w.x = pack_bf2(o0, o1);
        w.y = pack_bf2(o2, o3);
        *(uint2*)(h1 + (size_t)n * 64 + 2 * l32) = w;
    }
}

// ---------- conv2: heads=1 ch=32, fp32, 2 nodes/wave, depth-1 prefetch ----------
__global__ __launch_bounds__(256)
void k_conv2(const float* __restrict__ xl, const float* __restrict__ xr,
             const int* __restrict__ csr, const int* __restrict__ offs_end,
             const int* __restrict__ cnt, const float* __restrict__ att,
             const float* __restrict__ bias, float* __restrict__ out, int n_nodes) {
    int wave = threadIdx.x >> 6;
    int lane = threadIdx.x & 63;
    int half = lane >> 5;
    int c = lane & 31;
    int n = blockIdx.x * 8 + wave * 2 + half;
    bool nvalid = n < n_nodes;
    int nn = nvalid ? n : 0;
    int c_n = nvalid ? cnt[nn] : -1;     // total=0 for invalid
    int start = offs_end[nn] - max(c_n, 0);
    int total = c_n + 1;
    int t_other = __shfl_xor(total, 32);
    int tmax = max(total, t_other);
    float xr_v = xr[(size_t)nn * 32 + c];
    float att_v = att[c];
    float xj_cur = xl[(size_t)nn * 32 + c];             // j=0 self
    int src_n = (1 < total) ? csr[start] : nn;
    float s = 0.f, acc = 0.f;
    for (int j = 0; j < tmax; ++j) {
        float xj_next = xl[(size_t)src_n * 32 + c];
        int jn2 = j + 2;
        int src_n2 = (jn2 < total && jn2 > 0) ? csr[start + jn2 - 1] : nn;
        bool valid = j < total;
        float t = xj_cur + xr_v;
        float lk = fmaxf(t, 0.f) + 0.2f * fminf(t, 0.f);
        float p = att_v * lk;
#pragma unroll
        for (int mk = 16; mk >= 1; mk >>= 1) p += __shfl_xor(p, mk);
        float ez = valid ? exp2f(p * EXP_SHIFT_MUL - EXP_SHIFT_SUB) : 0.f;
        s += ez;
        acc += ez * xj_cur;
        xj_cur = xj_next; src_n = src_n2;
    }
    if (nvalid) {
        float o = acc / s + bias[c];
        out[(size_t)nn * 32 + c] = o > 0.f ? o : __expf(o) - 1.f;   // ELU
    }
}

// ---------- mean pool (batch sorted) ----------
__global__ __launch_bounds__(256)
void k_pool(const float* __restrict__ h2, const int* __restrict__ batch,
            float* __restrict__ pooled, float* __restrict__ gcnt, int n_nodes) {
    __shared__ float lp[NGRAPH * HID];
    __shared__ float lc[NGRAPH];
    for (int i = threadIdx.x; i < NGRAPH * HID; i += 256) lp[i] = 0.f;
    for (int i = threadIdx.x; i < NGRAPH; i += 256) lc[i] = 0.f;
    __syncthreads();
    int totalElems = n_nodes * HID;
    int per = (totalElems + gridDim.x - 1) / gridDim.x;
    int s0 = blockIdx.x * per;
    int s1 = min(s0 + per, totalElems);
    for (int i = s0 + threadIdx.x; i < s1; i += 256) {
        int n = i >> 5, cc = i & 31;
        int g = batch[n];
        atomicAdd(&lp[g * HID + cc], h2[i]);
        if (cc == 0) atomicAdd(&lc[g], 1.f);
    }
    __syncthreads();
    for (int i = threadIdx.x; i < NGRAPH * HID; i += 256)
        if (lp[i] != 0.f) atomicAdd(&pooled[i], lp[i]);
    for (int i = threadIdx.x; i < NGRAPH; i += 256)
        if (lc[i] != 0.f) atomicAdd(&gcnt[i], lc[i]);
}

// ---------- final FC + log_softmax ----------
__global__ void k_final(const float* __restrict__ pooled, const float* __restrict__ gcnt,
                        const float* __restrict__ Wfc, const float* __restrict__ bfc,
                        float* __restrict__ out) {
    int g = blockIdx.x * blockDim.x + threadIdx.x;
    if (g >= NGRAPH) return;
    float inv = 1.f / fmaxf(gcnt[g], 1.f);
    float z0 = bfc[0], z1 = bfc[1];
    for (int c = 0; c < HID; ++c) {
        float mv = pooled[g * HID + c] * inv;
        z0 += mv * Wfc[c * 2 + 0];
        z1 += mv * Wfc[c * 2 + 1];
    }
    float mx = fmaxf(z0, z1);
    float lse = mx + logf(expf(z0 - mx) + expf(z1 - mx));
    out[g * 2 + 0] = z0 - lse;
    out[g * 2 + 1] = z1 - lse;
}

extern "C" void kernel_launch(void* const* d_in, const int* in_sizes, int n_in,
                              void* d_out, int out_size, void* d_ws, size_t ws_size,
                              hipStream_t stream) {
    const float* x     = (const float*)d_in[0];
    const float* eattr = (const float*)d_in[1];
    const int*   eidx  = (const int*)d_in[2];
    const int*   batch = (const int*)d_in[3];
    const float* We    = (const float*)d_in[4];
    const float* be    = (const float*)d_in[5];
    const float* W1l   = (const float*)d_in[6];
    const float* b1l   = (const float*)d_in[7];
    const float* W1r   = (const float*)d_in[8];
    const float* b1r   = (const float*)d_in[9];
    const float* att1  = (const float*)d_in[10];
    const float* bias1 = (const float*)d_in[11];
    const float* W2l   = (const float*)d_in[12];
    const float* b2l   = (const float*)d_in[13];
    const float* W2r   = (const float*)d_in[14];
    const float* b2r   = (const float*)d_in[15];
    const float* att2  = (const float*)d_in[16];
    const float* bias2 = (const float*)d_in[17];
    const float* Wfc   = (const float*)d_in[18];
    const float* bfc   = (const float*)d_in[19];
    float* out = (float*)d_out;

    char* ws = (char*)d_ws;
    size_t off = 0;
    auto alloc = [&](size_t bytes) {
        void* p = ws + off;
        off += (bytes + 255) & ~size_t(255);
        return p;
    };
    int*      cnt    = (int*)     alloc(N_NODES * 4);
    int*      offs   = (int*)     alloc(N_NODES * 4);
    float*    ssum   = (float*)   alloc(N_NODES * 4);
    int*      csr    = (int*)     alloc(N_EDGES * 4);
    unsigned* xl1    = (unsigned*)alloc((size_t)N_NODES * 64 * 4);   // bf16 [N,128]
    unsigned* xr1    = (unsigned*)alloc((size_t)N_NODES * 64 * 4);
    unsigned* h1     = (unsigned*)alloc((size_t)N_NODES * 64 * 4);   // bf16 [N,128]
    float*    pooled = (float*)   alloc(NGRAPH * HID * 4);
    float*    gcnt   = (float*)   alloc(NGRAPH * 4);
    // xl1/xr1 dead after conv1 -> reuse region for conv2 fp32 tensors
    float* xl2 = (float*)xl1;
    float* xr2 = xl2 + (size_t)N_NODES * 32;
    float* h2  = xr2 + (size_t)N_NODES * 32;   // 19.2MB fits in xl1+xr1 (25.6MB)

    hipMemsetAsync(cnt, 0, N_NODES * 4, stream);
    hipMemsetAsync(ssum, 0, N_NODES * 4, stream);
    hipMemsetAsync(pooled, 0, NGRAPH * HID * 4, stream);
    hipMemsetAsync(gcnt, 0, NGRAPH * 4, stream);

    int ebl = (N_EDGES + 255) / 256;
    k_count<<<ebl, 256, 0, stream>>>(eidx, eattr, cnt, ssum, N_EDGES);
    k_scan<<<1, 1024, 0, stream>>>(cnt, offs, N_NODES);
    k_fill<<<ebl, 256, 0, stream>>>(eidx, offs, csr, N_EDGES);

    int gbl = (N_NODES + 63) / 64;   // 782
    k_mm1<<<gbl, 256, 0, stream>>>(x, ssum, cnt, We, be, W1l, b1l,
                                   (unsigned short*)xl1, N_NODES);
    k_mm1<<<gbl, 256, 0, stream>>>(x, ssum, cnt, We, be, W1r, b1r,
                                   (unsigned short*)xr1, N_NODES);

    k_conv1<<<(N_NODES + 3) / 4, 256, 0, stream>>>(
        xl1, xr1, csr, offs, cnt, att1, bias1, h1, N_NODES);

    k_mm2<<<gbl, 256, 0, stream>>>(h1, W2l, b2l, W2r, b2r, xl2, xr2, N_NODES);

    k_conv2<<<(N_NODES + 7) / 8, 256, 0, stream>>>(
        xl2, xr2, csr, offs, cnt, att2, bias2, h2, N_NODES);

    k_pool<<<256, 256, 0, stream>>>(h2, batch, pooled, gcnt, N_NODES);
    k_final<<<1, 128, 0, stream>>>(pooled, gcnt, Wfc, bfc, out);
}

// Round 12
// 402.869 us; speedup vs baseline: 1.8604x; 1.1772x over previous
//
#include <hip/hip_runtime.h>
#include <hip/hip_bf16.h>
#include <math.h>

#define N_NODES 50000
#define N_EDGES 800000
#define F_IN    116
#define HID     32
#define HEADS   4
#define NGRAPH  100
#define IN1     (F_IN + HID)    // 148
#define IN2     (HID * HEADS)   // 128
#define NB_SCAN ((N_NODES + 255) / 256)   // 196

// exp(x - 30) == exp2(x*log2e - 30*log2e)
#define EXP_SHIFT_MUL  1.44269504f
#define EXP_SHIFT_SUB  43.2808512f

typedef __attribute__((ext_vector_type(8))) short bf16x8;
typedef __attribute__((ext_vector_type(4))) float f32x4;

__device__ inline unsigned pack_bf2(float a, float b) {
    unsigned lo = __bfloat16_as_ushort(__float2bfloat16(a));
    unsigned hi = __bfloat16_as_ushort(__float2bfloat16(b));
    return lo | (hi << 16);
}

// ---------- CSR build ----------
__global__ void k_count(const int* __restrict__ ei, const float* __restrict__ attr,
                        int* __restrict__ cnt, float* __restrict__ ssum, int E) {
    int e = blockIdx.x * blockDim.x + threadIdx.x;
    if (e >= E) return;
    int d = ei[E + e];
    atomicAdd(&cnt[d], 1);
    atomicAdd(&ssum[d], attr[e]);
}

// ---------- hierarchical exclusive scan: offs = exclusive_prefix(cnt) ----------
__global__ __launch_bounds__(256)
void k_scan_a(const int* __restrict__ cnt, int* __restrict__ bsum, int n) {
    __shared__ int lds[256];
    int t = threadIdx.x;
    int i = blockIdx.x * 256 + t;
    int v = (i < n) ? cnt[i] : 0;
    lds[t] = v;
    __syncthreads();
#pragma unroll
    for (int off = 128; off >= 1; off >>= 1) {
        if (t < off) lds[t] += lds[t + off];
        __syncthreads();
    }
    if (t == 0) bsum[blockIdx.x] = lds[0];
}

__global__ __launch_bounds__(256)
void k_scan_b(int* __restrict__ bsum, int* __restrict__ boff) {
    __shared__ int lds[256];
    int t = threadIdx.x;
    int v = (t < NB_SCAN) ? bsum[t] : 0;
    lds[t] = v;
    __syncthreads();
#pragma unroll
    for (int off = 1; off < 256; off <<= 1) {
        int u = (t >= off) ? lds[t - off] : 0;
        __syncthreads();
        lds[t] += u;
        __syncthreads();
    }
    if (t < NB_SCAN) boff[t] = lds[t] - v;   // exclusive
}

__global__ __launch_bounds__(256)
void k_scan_c(const int* __restrict__ cnt, const int* __restrict__ boff,
              int* __restrict__ offs, int n) {
    __shared__ int lds[256];
    int t = threadIdx.x;
    int i = blockIdx.x * 256 + t;
    int v = (i < n) ? cnt[i] : 0;
    lds[t] = v;
    __syncthreads();
#pragma unroll
    for (int off = 1; off < 256; off <<= 1) {
        int u = (t >= off) ? lds[t - off] : 0;
        __syncthreads();
        lds[t] += u;
        __syncthreads();
    }
    if (i < n) offs[i] = boff[blockIdx.x] + lds[t] - v;   // exclusive
}

__global__ void k_fill(const int* __restrict__ ei, int* __restrict__ offs,
                       int* __restrict__ csr, int E) {
    int e = blockIdx.x * blockDim.x + threadIdx.x;
    if (e >= E) return;
    int d = ei[E + e];
    int pos = atomicAdd(&offs[d], 1);   // offs becomes "end" after this kernel
    csr[pos] = ei[e];
}

// ---------- MFMA GEMM 1: C[M][128] = hcat(x, edge_msg)[M][148] @ W + bias ----------
// Whole K resident in LDS (pad 148->168). Output bf16-packed u16.
#define KPAD1 168
__global__ __launch_bounds__(256)
void k_mm1(const float* __restrict__ x, const float* __restrict__ ssum,
           const int* __restrict__ cnt, const float* __restrict__ We,
           const float* __restrict__ be, const float* __restrict__ W,
           const float* __restrict__ bias, unsigned short* __restrict__ Cb, int M) {
    __shared__ short As[64][KPAD1];
    __shared__ short Ws[128][KPAD1];
    int tid = threadIdx.x;
    int rowBase = blockIdx.x * 64;
    // stage A (64 rows x 84 bf16-pairs): fp32 -> bf16, fused edge_msg for k>=116
    {
        int r = tid >> 2;
        int p0 = tid & 3;
        int row = rowBase + r;
        bool rv = row < M;
        float ss = rv ? ssum[row] : 0.f;
        float cf = rv ? (float)cnt[row] : 0.f;
        const float* xrp = x + (size_t)row * F_IN;
#pragma unroll
        for (int i = 0; i < 21; ++i) {
            int p = p0 + i * 4;
            int k = 2 * p;
            float v0 = 0.f, v1 = 0.f;
            if (rv && k < IN1) {
                if (k < F_IN) {
                    float2 t = *(const float2*)(xrp + k);
                    v0 = t.x; v1 = t.y;
                } else {
                    int j = k - F_IN;
                    v0 = We[j] * ss + be[j] * cf;
                    v1 = We[j + 1] * ss + be[j + 1] * cf;
                }
            }
            ((int*)&As[r][0])[p] = (int)pack_bf2(v0, v1);
        }
    }
    // stage W^T (128 cols x 84 bf16-pairs)
    {
        int c = tid & 127;
        int ph = tid >> 7;
#pragma unroll
        for (int i = 0; i < 42; ++i) {
            int p = ph + 2 * i;
            int k = 2 * p;
            float v0 = (k < IN1) ? W[k * 128 + c] : 0.f;
            float v1 = (k + 1 < IN1) ? W[(k + 1) * 128 + c] : 0.f;
            ((int*)&Ws[c][0])[p] = (int)pack_bf2(v0, v1);
        }
    }
    __syncthreads();

    int wid = tid >> 6, l = tid & 63;
    int wm = wid >> 1, wn = wid & 1;
    int mBase = wm * 32, nBase = wn * 64;
    int lr = l & 15, lg = l >> 4;
    f32x4 acc[2][4] = {};
#pragma unroll
    for (int ks = 0; ks < 5; ++ks) {
        int k0 = ks * 32 + lg * 8;
        bf16x8 a0 = *(bf16x8*)&As[mBase + lr][k0];
        bf16x8 a1 = *(bf16x8*)&As[mBase + 16 + lr][k0];
        bf16x8 b0 = *(bf16x8*)&Ws[nBase + lr][k0];
        bf16x8 b1 = *(bf16x8*)&Ws[nBase + 16 + lr][k0];
        bf16x8 b2 = *(bf16x8*)&Ws[nBase + 32 + lr][k0];
        bf16x8 b3 = *(bf16x8*)&Ws[nBase + 48 + lr][k0];
        acc[0][0] = __builtin_amdgcn_mfma_f32_16x16x32_bf16(a0, b0, acc[0][0], 0, 0, 0);
        acc[0][1] = __builtin_amdgcn_mfma_f32_16x16x32_bf16(a0, b1, acc[0][1], 0, 0, 0);
        acc[0][2] = __builtin_amdgcn_mfma_f32_16x16x32_bf16(a0, b2, acc[0][2], 0, 0, 0);
        acc[0][3] = __builtin_amdgcn_mfma_f32_16x16x32_bf16(a0, b3, acc[0][3], 0, 0, 0);
        acc[1][0] = __builtin_amdgcn_mfma_f32_16x16x32_bf16(a1, b0, acc[1][0], 0, 0, 0);
        acc[1][1] = __builtin_amdgcn_mfma_f32_16x16x32_bf16(a1, b1, acc[1][1], 0, 0, 0);
        acc[1][2] = __builtin_amdgcn_mfma_f32_16x16x32_bf16(a1, b2, acc[1][2], 0, 0, 0);
        acc[1][3] = __builtin_amdgcn_mfma_f32_16x16x32_bf16(a1, b3, acc[1][3], 0, 0, 0);
    }
#pragma unroll
    for (int mf = 0; mf < 2; ++mf)
#pragma unroll
        for (int nf = 0; nf < 4; ++nf) {
            int col = nBase + nf * 16 + lr;
            float bs = bias[col];
#pragma unroll
            for (int r = 0; r < 4; ++r) {
                int row = rowBase + mBase + mf * 16 + lg * 4 + r;
                if (row < M)
                    Cb[(size_t)row * 128 + col] =
                        __bfloat16_as_ushort(__float2bfloat16(acc[mf][nf][r] + bs));
            }
        }
}

// ---------- MFMA GEMM 2 (fused l|r): [xl2|xr2] = h1[M][128] @ [W2l|W2r] + b ----------
#define KPAD2 136
__global__ __launch_bounds__(256)
void k_mm2(const unsigned* __restrict__ h1, const float* __restrict__ Wl,
           const float* __restrict__ bl, const float* __restrict__ Wr,
           const float* __restrict__ br, float* __restrict__ xl2,
           float* __restrict__ xr2, int M) {
    __shared__ short As[64][KPAD2];
    __shared__ short Ws[64][KPAD2];
    int tid = threadIdx.x;
    int rowBase = blockIdx.x * 64;
    // stage A from bf16-packed h1 (64 rows x 68 uint slots)
    {
        int r = tid >> 2;
        int s0 = tid & 3;
        int row = rowBase + r;
        bool rv = row < M;
#pragma unroll
        for (int i = 0; i < 17; ++i) {
            int slot = s0 + 4 * i;
            unsigned u = (rv && slot < 64) ? h1[(size_t)row * 64 + slot] : 0u;
            ((int*)&As[r][0])[slot] = (int)u;
        }
    }
    // stage [W2l|W2r]^T (64 cols x 68 pairs)
    {
        int c = tid & 63;
        int ph = tid >> 6;
#pragma unroll
        for (int i = 0; i < 17; ++i) {
            int p = ph + 4 * i;
            int k = 2 * p;
            float v0 = 0.f, v1 = 0.f;
            if (k < IN2) {
                if (c < 32) { v0 = Wl[k * 32 + c]; v1 = Wl[(k + 1) * 32 + c]; }
                else        { v0 = Wr[k * 32 + c - 32]; v1 = Wr[(k + 1) * 32 + c - 32]; }
            }
            ((int*)&Ws[c][0])[p] = (int)pack_bf2(v0, v1);
        }
    }
    __syncthreads();

    int wid = tid >> 6, l = tid & 63;
    int wm = wid >> 1, wn = wid & 1;
    int mBase = wm * 32, nBase = wn * 32;
    int lr = l & 15, lg = l >> 4;
    f32x4 acc[2][2] = {};
#pragma unroll
    for (int ks = 0; ks < 4; ++ks) {
        int k0 = ks * 32 + lg * 8;
        bf16x8 a0 = *(bf16x8*)&As[mBase + lr][k0];
        bf16x8 a1 = *(bf16x8*)&As[mBase + 16 + lr][k0];
        bf16x8 b0 = *(bf16x8*)&Ws[nBase + lr][k0];
        bf16x8 b1 = *(bf16x8*)&Ws[nBase + 16 + lr][k0];
        acc[0][0] = __builtin_amdgcn_mfma_f32_16x16x32_bf16(a0, b0, acc[0][0], 0, 0, 0);
        acc[0][1] = __builtin_amdgcn_mfma_f32_16x16x32_bf16(a0, b1, acc[0][1], 0, 0, 0);
        acc[1][0] = __builtin_amdgcn_mfma_f32_16x16x32_bf16(a1, b0, acc[1][0], 0, 0, 0);
        acc[1][1] = __builtin_amdgcn_mfma_f32_16x16x32_bf16(a1, b1, acc[1][1], 0, 0, 0);
    }
#pragma unroll
    for (int mf = 0; mf < 2; ++mf)
#pragma unroll
        for (int nf = 0; nf < 2; ++nf) {
            int cg = nBase + nf * 16 + lr;
#pragma unroll
            for (int r = 0; r < 4; ++r) {
                int row = rowBase + mBase + mf * 16 + lg * 4 + r;
                if (row < M) {
                    float v = acc[mf][nf][r];
                    if (cg < 32) xl2[(size_t)row * 32 + cg] = v + bl[cg];
                    else         xr2[(size_t)row * 32 + cg - 32] = v + br[cg - 32];
                }
            }
        }
}

// ---------- conv1: heads=4 ch=32, bf16 inputs, 2 edges/iter, depth-2 prefetch ----------
// xl/xr: bf16-packed [N,64] uints. out h1: bf16-packed [N,64] uints.
__global__ __launch_bounds__(256)
void k_conv1(const unsigned* __restrict__ xl, const unsigned* __restrict__ xr,
             const int* __restrict__ csr, const int* __restrict__ offs_end,
             const int* __restrict__ cnt, const float* __restrict__ att,
             const float* __restrict__ bias, unsigned* __restrict__ h1, int n_nodes) {
    int wave = threadIdx.x >> 6;
    int lane = threadIdx.x & 63;
    int half = lane >> 5;
    int l32 = lane & 31;
    int n = blockIdx.x * 4 + wave;
    if (n >= n_nodes) return;
    int c_n = cnt[n];
    int start = offs_end[n] - c_n;
    int total = c_n + 1;                     // + self loop

    uint2 urv = *(const uint2*)(xr + (size_t)n * 64 + 2 * l32);
    float xr0 = __uint_as_float(urv.x << 16);
    float xr1 = __uint_as_float(urv.x & 0xffff0000u);
    float xr2v = __uint_as_float(urv.y << 16);
    float xr3 = __uint_as_float(urv.y & 0xffff0000u);
    float4 av = *(const float4*)(att + 4 * l32);

    int tmax = (total + 1) >> 1;
    // item(t) = 2t + half; item 0 = self, item i>=1 -> csr[start+i-1]
    int item0 = half;
    bool v_cur = item0 < total;
    int src_cur = (item0 == 0 || !v_cur) ? n : csr[start];
    uint2 u_cur = *(const uint2*)(xl + (size_t)src_cur * 64 + 2 * l32);
    int item1 = 2 + half;
    bool v_n = item1 < total;
    int src_n = v_n ? csr[start + item1 - 1] : n;

    float s = 0.f, a0 = 0.f, a1 = 0.f, a2 = 0.f, a3 = 0.f;
    for (int t = 0; t < tmax; ++t) {
        uint2 u_next = *(const uint2*)(xl + (size_t)src_n * 64 + 2 * l32);
        int item2 = 2 * (t + 2) + half;
        bool v_n2 = item2 < total;
        int src_n2 = v_n2 ? csr[start + item2 - 1] : n;

        float x0 = __uint_as_float(u_cur.x << 16);
        float x1 = __uint_as_float(u_cur.x & 0xffff0000u);
        float x2 = __uint_as_float(u_cur.y << 16);
        float x3 = __uint_as_float(u_cur.y & 0xffff0000u);
        float t0 = x0 + xr0, t1 = x1 + xr1, t2 = x2 + xr2v, t3 = x3 + xr3;
        float p = av.x * (fmaxf(t0, 0.f) + 0.2f * fminf(t0, 0.f))
                + av.y * (fmaxf(t1, 0.f) + 0.2f * fminf(t1, 0.f))
                + av.z * (fmaxf(t2, 0.f) + 0.2f * fminf(t2, 0.f))
                + av.w * (fmaxf(t3, 0.f) + 0.2f * fminf(t3, 0.f));
        // reduce over 8-lane head group
        p += __shfl_xor(p, 1);
        p += __shfl_xor(p, 2);
        p += __shfl_xor(p, 4);
        float ez = v_cur ? exp2f(p * EXP_SHIFT_MUL - EXP_SHIFT_SUB) : 0.f;
        s += ez;
        a0 += ez * x0; a1 += ez * x1; a2 += ez * x2; a3 += ez * x3;

        u_cur = u_next; v_cur = v_n; v_n = v_n2; src_n = src_n2;
    }
    // merge the two halves (even/odd edge partial sums)
    s  += __shfl_xor(s, 32);
    a0 += __shfl_xor(a0, 32);
    a1 += __shfl_xor(a1, 32);
    a2 += __shfl_xor(a2, 32);
    a3 += __shfl_xor(a3, 32);
    if (half == 0) {
        float inv = 1.f / s;
        float4 bv = *(const float4*)(bias + 4 * l32);
        float o0 = a0 * inv + bv.x;
        float o1 = a1 * inv + bv.y;
        float o2 = a2 * inv + bv.z;
        float o3 = a3 * inv + bv.w;
        o0 = o0 > 0.f ? o0 : __expf(o0) - 1.f;   // ELU
        o1 = o1 > 0.f ? o1 : __expf(o1) - 1.f;
        o2 = o2 > 0.f ? o2 : __expf(o2) - 1.f;
        o3 = o3 > 0.f ? o3 : __expf(o3) - 1.f;
        uint2 w;
        w.x = pack_bf2(o0, o1);
        w.y = pack_bf2(o2, o3);
        *(uint2*)(h1 + (size_t)n * 64 + 2 * l32) = w;
    }
}

// ---------- conv2: heads=1 ch=32, fp32, 2 nodes/wave, depth-1 prefetch ----------
__global__ __launch_bounds__(256)
void k_conv2(const float* __restrict__ xl, const float* __restrict__ xr,
             const int* __restrict__ csr, const int* __restrict__ offs_end,
             const int* __restrict__ cnt, const float* __restrict__ att,
             const float* __restrict__ bias, float* __restrict__ out, int n_nodes) {
    int wave = threadIdx.x >> 6;
    int lane = threadIdx.x & 63;
    int half = lane >> 5;
    int c = lane & 31;
    int n = blockIdx.x * 8 + wave * 2 + half;
    bool nvalid = n < n_nodes;
    int nn = nvalid ? n : 0;
    int c_n = nvalid ? cnt[nn] : -1;     // total=0 for invalid
    int start = offs_end[nn] - max(c_n, 0);
    int total = c_n + 1;
    int t_other = __shfl_xor(total, 32);
    int tmax = max(total, t_other);
    float xr_v = xr[(size_t)nn * 32 + c];
    float att_v = att[c];
    float xj_cur = xl[(size_t)nn * 32 + c];             // j=0 self
    int src_n = (1 < total) ? csr[start] : nn;
    float s = 0.f, acc = 0.f;
    for (int j = 0; j < tmax; ++j) {
        float xj_next = xl[(size_t)src_n * 32 + c];
        int jn2 = j + 2;
        int src_n2 = (jn2 < total && jn2 > 0) ? csr[start + jn2 - 1] : nn;
        bool valid = j < total;
        float t = xj_cur + xr_v;
        float lk = fmaxf(t, 0.f) + 0.2f * fminf(t, 0.f);
        float p = att_v * lk;
#pragma unroll
        for (int mk = 16; mk >= 1; mk >>= 1) p += __shfl_xor(p, mk);
        float ez = valid ? exp2f(p * EXP_SHIFT_MUL - EXP_SHIFT_SUB) : 0.f;
        s += ez;
        acc += ez * xj_cur;
        xj_cur = xj_next; src_n = src_n2;
    }
    if (nvalid) {
        float o = acc / s + bias[c];
        out[(size_t)nn * 32 + c] = o > 0.f ? o : __expf(o) - 1.f;   // ELU
    }
}

// ---------- mean pool (batch sorted) ----------
__global__ __launch_bounds__(256)
void k_pool(const float* __restrict__ h2, const int* __restrict__ batch,
            float* __restrict__ pooled, float* __restrict__ gcnt, int n_nodes) {
    __shared__ float lp[NGRAPH * HID];
    __shared__ float lc[NGRAPH];
    for (int i = threadIdx.x; i < NGRAPH * HID; i += 256) lp[i] = 0.f;
    for (int i = threadIdx.x; i < NGRAPH; i += 256) lc[i] = 0.f;
    __syncthreads();
    int totalElems = n_nodes * HID;
    int per = (totalElems + gridDim.x - 1) / gridDim.x;
    int s0 = blockIdx.x * per;
    int s1 = min(s0 + per, totalElems);
    for (int i = s0 + threadIdx.x; i < s1; i += 256) {
        int n = i >> 5, cc = i & 31;
        int g = batch[n];
        atomicAdd(&lp[g * HID + cc], h2[i]);
        if (cc == 0) atomicAdd(&lc[g], 1.f);
    }
    __syncthreads();
    for (int i = threadIdx.x; i < NGRAPH * HID; i += 256)
        if (lp[i] != 0.f) atomicAdd(&pooled[i], lp[i]);
    for (int i = threadIdx.x; i < NGRAPH; i += 256)
        if (lc[i] != 0.f) atomicAdd(&gcnt[i], lc[i]);
}

// ---------- final FC + log_softmax ----------
__global__ void k_final(const float* __restrict__ pooled, const float* __restrict__ gcnt,
                        const float* __restrict__ Wfc, const float* __restrict__ bfc,
                        float* __restrict__ out) {
    int g = blockIdx.x * blockDim.x + threadIdx.x;
    if (g >= NGRAPH) return;
    float inv = 1.f / fmaxf(gcnt[g], 1.f);
    float z0 = bfc[0], z1 = bfc[1];
    for (int c = 0; c < HID; ++c) {
        float mv = pooled[g * HID + c] * inv;
        z0 += mv * Wfc[c * 2 + 0];
        z1 += mv * Wfc[c * 2 + 1];
    }
    float mx = fmaxf(z0, z1);
    float lse = mx + logf(expf(z0 - mx) + expf(z1 - mx));
    out[g * 2 + 0] = z0 - lse;
    out[g * 2 + 1] = z1 - lse;
}

extern "C" void kernel_launch(void* const* d_in, const int* in_sizes, int n_in,
                              void* d_out, int out_size, void* d_ws, size_t ws_size,
                              hipStream_t stream) {
    const float* x     = (const float*)d_in[0];
    const float* eattr = (const float*)d_in[1];
    const int*   eidx  = (const int*)d_in[2];
    const int*   batch = (const int*)d_in[3];
    const float* We    = (const float*)d_in[4];
    const float* be    = (const float*)d_in[5];
    const float* W1l   = (const float*)d_in[6];
    const float* b1l   = (const float*)d_in[7];
    const float* W1r   = (const float*)d_in[8];
    const float* b1r   = (const float*)d_in[9];
    const float* att1  = (const float*)d_in[10];
    const float* bias1 = (const float*)d_in[11];
    const float* W2l   = (const float*)d_in[12];
    const float* b2l   = (const float*)d_in[13];
    const float* W2r   = (const float*)d_in[14];
    const float* b2r   = (const float*)d_in[15];
    const float* att2  = (const float*)d_in[16];
    const float* bias2 = (const float*)d_in[17];
    const float* Wfc   = (const float*)d_in[18];
    const float* bfc   = (const float*)d_in[19];
    float* out = (float*)d_out;

    char* ws = (char*)d_ws;
    size_t off = 0;
    auto alloc = [&](size_t bytes) {
        void* p = ws + off;
        off += (bytes + 255) & ~size_t(255);
        return p;
    };
    // cnt+ssum adjacent (one memset); pooled+gcnt adjacent (one memset)
    int*      cnt    = (int*)     alloc(N_NODES * 4);
    float*    ssum   = (float*)   alloc(N_NODES * 4);
    int*      offs   = (int*)     alloc(N_NODES * 4);
    int*      bsum   = (int*)     alloc(NB_SCAN * 4);
    int*      boff   = (int*)     alloc(NB_SCAN * 4);
    int*      csr    = (int*)     alloc(N_EDGES * 4);
    unsigned* xl1    = (unsigned*)alloc((size_t)N_NODES * 64 * 4);   // bf16 [N,128]
    unsigned* xr1    = (unsigned*)alloc((size_t)N_NODES * 64 * 4);
    unsigned* h1     = (unsigned*)alloc((size_t)N_NODES * 64 * 4);   // bf16 [N,128]
    float*    pooled = (float*)   alloc(NGRAPH * (HID + 1) * 4);
    float*    gcnt   = pooled + NGRAPH * HID;
    // xl1/xr1 dead after conv1 -> reuse region for conv2 fp32 tensors
    float* xl2 = (float*)xl1;
    float* xr2 = xl2 + (size_t)N_NODES * 32;
    float* h2  = xr2 + (size_t)N_NODES * 32;   // 19.2MB fits in xl1+xr1 (25.6MB)

    hipMemsetAsync(cnt, 0, 2 * N_NODES * 4 + 256, stream);     // cnt + ssum (adjacent, 256B pad)
    hipMemsetAsync(pooled, 0, NGRAPH * (HID + 1) * 4, stream); // pooled + gcnt

    int ebl = (N_EDGES + 255) / 256;
    k_count<<<ebl, 256, 0, stream>>>(eidx, eattr, cnt, ssum, N_EDGES);
    k_scan_a<<<NB_SCAN, 256, 0, stream>>>(cnt, bsum, N_NODES);
    k_scan_b<<<1, 256, 0, stream>>>(bsum, boff);
    k_scan_c<<<NB_SCAN, 256, 0, stream>>>(cnt, boff, offs, N_NODES);
    k_fill<<<ebl, 256, 0, stream>>>(eidx, offs, csr, N_EDGES);

    int gbl = (N_NODES + 63) / 64;   // 782
    k_mm1<<<gbl, 256, 0, stream>>>(x, ssum, cnt, We, be, W1l, b1l,
                                   (unsigned short*)xl1, N_NODES);
    k_mm1<<<gbl, 256, 0, stream>>>(x, ssum, cnt, We, be, W1r, b1r,
                                   (unsigned short*)xr1, N_NODES);

    k_conv1<<<(N_NODES + 3) / 4, 256, 0, stream>>>(
        xl1, xr1, csr, offs, cnt, att1, bias1, h1, N_NODES);

    k_mm2<<<gbl, 256, 0, stream>>>(h1, W2l, b2l, W2r, b2r, xl2, xr2, N_NODES);

    k_conv2<<<(N_NODES + 7) / 8, 256, 0, stream>>>(
        xl2, xr2, csr, offs, cnt, att2, bias2, h2, N_NODES);

    k_pool<<<256, 256, 0, stream>>>(h2, batch, pooled, gcnt, N_NODES);
    k_final<<<1, 128, 0, stream>>>(pooled, gcnt, Wfc, bfc, out);
}